// Round 1
// baseline (490.006 us; speedup 1.0000x reference)
//
#include <hip/hip_runtime.h>
#include <hip/hip_bf16.h>
#include <cstdint>
#include <cstddef>

#define NHEAD 12
#define TSEQ  4096
#define CDIM  768
#define DHEAD 64

typedef __attribute__((ext_vector_type(8))) short bf16x8;
typedef __attribute__((ext_vector_type(4))) float f32x4;

typedef __attribute__((address_space(1))) void gvoid;
typedef __attribute__((address_space(3))) void lvoid;

static __device__ __forceinline__ unsigned short f2bf(float f) {
    union { float f; uint32_t u; } v; v.f = f;
    uint32_t u = v.u;
    u += 0x7fffu + ((u >> 16) & 1u);   // RNE
    return (unsigned short)(u >> 16);
}

static __device__ __forceinline__ f32x4 mfma16(bf16x8 a, bf16x8 b, f32x4 c) {
    return __builtin_amdgcn_mfma_f32_16x16x32_bf16(a, b, c, 0, 0, 0);
}

// ---------------- conversion kernels ----------------

__global__ void cvt_f32_bf16(const float* __restrict__ in, unsigned short* __restrict__ out, int n4) {
    int i = blockIdx.x * blockDim.x + threadIdx.x;
    int stride = gridDim.x * blockDim.x;
    for (int idx = i; idx < n4; idx += stride) {
        float4 v = reinterpret_cast<const float4*>(in)[idx];
        ushort4 o;
        o.x = f2bf(v.x); o.y = f2bf(v.y); o.z = f2bf(v.z); o.w = f2bf(v.w);
        reinterpret_cast<ushort4*>(out)[idx] = o;
    }
}

// W [K][N] f32  ->  Wt [N][K] bf16
__global__ void transpose_cvt(const float* __restrict__ W, unsigned short* __restrict__ Wt,
                              int K, int N) {
    __shared__ float tile[32][33];
    int n0 = blockIdx.x * 32;
    int k0 = blockIdx.y * 32;
    int tx = threadIdx.x & 31;
    int ty = threadIdx.x >> 5;   // 0..7
    #pragma unroll
    for (int r = ty; r < 32; r += 8)
        tile[r][tx] = W[(size_t)(k0 + r) * N + n0 + tx];
    __syncthreads();
    #pragma unroll
    for (int r = ty; r < 32; r += 8)
        Wt[(size_t)(n0 + r) * K + k0 + tx] = f2bf(tile[tx][r]);
}

// ---------------- GEMM core (A [M][K] bf16, Bt [N][K] bf16) ----------------
// MODE 0: qkv epilogue -> Q[h][t][d], K[h][t][d], Vt[h][d][t] (bf16, +bias)
// MODE 1: proj epilogue -> Out f32 [M][N] (+bias)

template<int MODE>
__global__ __launch_bounds__(256)
void gemm_bt(const unsigned short* __restrict__ A,
             const unsigned short* __restrict__ Bt,
             const float* __restrict__ bias,
             unsigned short* __restrict__ Qb,
             unsigned short* __restrict__ Kb,
             unsigned short* __restrict__ Vt,
             float* __restrict__ Out,
             int M, int N, int K)
{
    __shared__ __align__(16) unsigned short As[128 * 32];
    __shared__ __align__(16) unsigned short Bs[128 * 32];

    const int tid  = threadIdx.x;
    const int lane = tid & 63;
    const int w    = tid >> 6;       // 4 waves
    const int wr   = w >> 1, wc = w & 1;
    const int row0 = blockIdx.x * 128;
    const int col0 = blockIdx.y * 128;
    const int l16  = lane & 15;
    const int lhi  = lane >> 4;

    f32x4 acc[4][4] = {};

    for (int k0 = 0; k0 < K; k0 += 32) {
        __syncthreads();   // previous iteration's LDS reads done
        #pragma unroll
        for (int r = 0; r < 2; ++r) {
            int b    = r * 4096 + w * 1024 + lane * 16;   // byte offset in 8KB tile
            int trow = b >> 6;                            // tile row (64B per row)
            int koff = b & 63;                            // byte offset within row
            const char* gA = (const char*)A  + ((size_t)(row0 + trow) * K + k0) * 2 + koff;
            const char* gB = (const char*)Bt + ((size_t)(col0 + trow) * K + k0) * 2 + koff;
            __builtin_amdgcn_global_load_lds((gvoid*)gA,
                (lvoid*)((char*)As + r * 4096 + w * 1024), 16, 0, 0);
            __builtin_amdgcn_global_load_lds((gvoid*)gB,
                (lvoid*)((char*)Bs + r * 4096 + w * 1024), 16, 0, 0);
        }
        __syncthreads();   // drains vmcnt(0): staged data visible

        bf16x8 a[4], bfr[4];
        #pragma unroll
        for (int m = 0; m < 4; ++m) {
            int row = wr * 64 + m * 16 + l16;
            a[m] = *reinterpret_cast<const bf16x8*>(&As[row * 32 + lhi * 8]);
        }
        #pragma unroll
        for (int n = 0; n < 4; ++n) {
            int col = wc * 64 + n * 16 + l16;
            bfr[n] = *reinterpret_cast<const bf16x8*>(&Bs[col * 32 + lhi * 8]);
        }
        #pragma unroll
        for (int m = 0; m < 4; ++m)
            #pragma unroll
            for (int n = 0; n < 4; ++n)
                acc[m][n] = mfma16(a[m], bfr[n], acc[m][n]);
    }

    // epilogue: C[row][col], row = trow_base + (lhi*4 + j), col = ncol
    #pragma unroll
    for (int m = 0; m < 4; ++m) {
        int trow = row0 + wr * 64 + m * 16 + lhi * 4;
        #pragma unroll
        for (int n = 0; n < 4; ++n) {
            int ncol = col0 + wc * 64 + n * 16 + l16;
            float bv = bias[ncol];
            #pragma unroll
            for (int j = 0; j < 4; ++j) {
                float v = acc[m][n][j] + bv;
                int t = trow + j;
                if (MODE == 0) {
                    unsigned short hv = f2bf(v);
                    if (ncol < 768) {
                        int hh = ncol >> 6, d = ncol & 63;
                        Qb[((size_t)hh * TSEQ + t) * 64 + d] = hv;
                    } else if (ncol < 1536) {
                        int c = ncol - 768; int hh = c >> 6, d = c & 63;
                        Kb[((size_t)hh * TSEQ + t) * 64 + d] = hv;
                    } else {
                        int c = ncol - 1536; int hh = c >> 6, d = c & 63;
                        Vt[((size_t)hh * 64 + d) * TSEQ + t] = hv;
                    }
                } else {
                    Out[(size_t)t * N + ncol] = v;
                }
            }
        }
    }
}

// ---------------- flash attention (causal) ----------------
// grid: 12 heads * 32 q-blocks of 128; block = 256 threads = 4 waves,
// wave w owns q rows [qb*128 + w*32, +32). KV tiles of 32. No __syncthreads
// (waves have different trip counts; Plds regions are disjoint per wave).

__global__ __launch_bounds__(256)
void attn_fwd(const unsigned short* __restrict__ Qb,
              const unsigned short* __restrict__ Kb,
              const unsigned short* __restrict__ Vt,
              unsigned short* __restrict__ Y)
{
    __shared__ __align__(16) unsigned short Plds[4][32 * 32];

    const int tid  = threadIdx.x;
    const int lane = tid & 63;
    const int w    = tid >> 6;
    const int h    = blockIdx.x / 32;
    const int qblk = blockIdx.x % 32;
    const int q0   = qblk * 128 + w * 32;
    const int l16  = lane & 15, lhi = lane >> 4;

    const unsigned short* Qh = Qb + (size_t)h * TSEQ * 64;
    const unsigned short* Kh = Kb + (size_t)h * TSEQ * 64;
    const unsigned short* Vh = Vt + (size_t)h * 64 * TSEQ;

    // Q fragments (A operand): [m-frag][k-step]
    bf16x8 qf[2][2];
    #pragma unroll
    for (int m = 0; m < 2; ++m)
        #pragma unroll
        for (int s = 0; s < 2; ++s)
            qf[m][s] = *reinterpret_cast<const bf16x8*>(
                &Qh[(size_t)(q0 + m * 16 + l16) * 64 + s * 32 + lhi * 8]);

    f32x4 o[2][4] = {};
    float mrun[2][4], lrun[2][4];
    #pragma unroll
    for (int m = 0; m < 2; ++m)
        #pragma unroll
        for (int j = 0; j < 4; ++j) { mrun[m][j] = -1e30f; lrun[m][j] = 0.f; }

    const int ntiles = q0 / 32 + 1;
    for (int kt = 0; kt < ntiles; ++kt) {
        const int kv0 = kt * 32;
        // ---- S = Q K^T over d=64 (2 MFMA K-steps) ----
        f32x4 s[2][2] = {};
        #pragma unroll
        for (int ss = 0; ss < 2; ++ss) {
            bf16x8 kf[2];
            #pragma unroll
            for (int n = 0; n < 2; ++n)
                kf[n] = *reinterpret_cast<const bf16x8*>(
                    &Kh[(size_t)(kv0 + n * 16 + l16) * 64 + ss * 32 + lhi * 8]);
            #pragma unroll
            for (int m = 0; m < 2; ++m)
                #pragma unroll
                for (int n = 0; n < 2; ++n)
                    s[m][n] = mfma16(qf[m][ss], kf[n], s[m][n]);
        }
        const bool diag = (kv0 == q0);

        // ---- online softmax (per q-row = (m, lhi*4+j)) ----
        #pragma unroll
        for (int m = 0; m < 2; ++m) {
            #pragma unroll
            for (int j = 0; j < 4; ++j) {
                float s0 = s[m][0][j] * 0.125f;
                float s1 = s[m][1][j] * 0.125f;
                if (diag) {
                    int q = q0 + m * 16 + lhi * 4 + j;
                    if (kv0 + l16 > q)      s0 = -1e30f;
                    if (kv0 + 16 + l16 > q) s1 = -1e30f;
                }
                float mx = fmaxf(s0, s1);
                #pragma unroll
                for (int off = 8; off >= 1; off >>= 1)
                    mx = fmaxf(mx, __shfl_xor(mx, off));
                float mnew = fmaxf(mrun[m][j], mx);
                float corr = __expf(mrun[m][j] - mnew);
                float p0 = __expf(s0 - mnew);
                float p1 = __expf(s1 - mnew);
                float ps = p0 + p1;
                #pragma unroll
                for (int off = 8; off >= 1; off >>= 1)
                    ps += __shfl_xor(ps, off);
                lrun[m][j] = lrun[m][j] * corr + ps;
                mrun[m][j] = mnew;
                #pragma unroll
                for (int df = 0; df < 4; ++df)
                    o[m][df][j] *= corr;
                int prow = m * 16 + lhi * 4 + j;
                Plds[w][prow * 32 + l16]      = f2bf(p0);
                Plds[w][prow * 32 + 16 + l16] = f2bf(p1);
            }
        }
        asm volatile("s_waitcnt lgkmcnt(0)" ::: "memory");

        // ---- O += P V ----
        bf16x8 pa[2];
        #pragma unroll
        for (int m = 0; m < 2; ++m)
            pa[m] = *reinterpret_cast<const bf16x8*>(
                &Plds[w][(m * 16 + l16) * 32 + lhi * 8]);
        #pragma unroll
        for (int df = 0; df < 4; ++df) {
            bf16x8 vf = *reinterpret_cast<const bf16x8*>(
                &Vh[(size_t)(df * 16 + l16) * TSEQ + kv0 + lhi * 8]);
            #pragma unroll
            for (int m = 0; m < 2; ++m)
                o[m][df] = mfma16(pa[m], vf, o[m][df]);
        }
    }

    // ---- epilogue: y[t][h*64+d] bf16 ----
    #pragma unroll
    for (int m = 0; m < 2; ++m) {
        #pragma unroll
        for (int df = 0; df < 4; ++df) {
            #pragma unroll
            for (int j = 0; j < 4; ++j) {
                float v = o[m][df][j] / lrun[m][j];
                int t = q0 + m * 16 + lhi * 4 + j;
                int c = h * 64 + df * 16 + l16;
                Y[(size_t)t * CDIM + c] = f2bf(v);
            }
        }
    }
}

// ---------------- launch ----------------

extern "C" void kernel_launch(void* const* d_in, const int* in_sizes, int n_in,
                              void* d_out, int out_size, void* d_ws, size_t ws_size,
                              hipStream_t stream) {
    const float* x      = (const float*)d_in[0];
    const float* w_attn = (const float*)d_in[1];
    const float* b_attn = (const float*)d_in[2];
    const float* w_proj = (const float*)d_in[3];
    const float* b_proj = (const float*)d_in[4];
    float* out = (float*)d_out;

    char* ws = (char*)d_ws;
    unsigned short* xb  = (unsigned short*)(ws + 0);         // 4096*768
    unsigned short* WaT = (unsigned short*)(ws + 6291456);   // 2304*768
    unsigned short* WpT = (unsigned short*)(ws + 9830400);   // 768*768
    unsigned short* Qb  = (unsigned short*)(ws + 11010048);  // 12*4096*64
    unsigned short* Kb  = (unsigned short*)(ws + 17301504);  // 12*4096*64
    unsigned short* Vt  = (unsigned short*)(ws + 23592960);  // 12*64*4096
    unsigned short* Yb  = (unsigned short*)(ws + 29884416);  // 4096*768

    cvt_f32_bf16<<<2048, 256, 0, stream>>>(x, xb, TSEQ * CDIM / 4);
    transpose_cvt<<<dim3(2304 / 32, 768 / 32), 256, 0, stream>>>(w_attn, WaT, 768, 2304);
    transpose_cvt<<<dim3(768 / 32, 768 / 32), 256, 0, stream>>>(w_proj, WpT, 768, 768);

    gemm_bt<0><<<dim3(TSEQ / 128, 2304 / 128), 256, 0, stream>>>(
        xb, WaT, b_attn, Qb, Kb, Vt, nullptr, TSEQ, 2304, CDIM);

    attn_fwd<<<NHEAD * (TSEQ / 128), 256, 0, stream>>>(Qb, Kb, Vt, Yb);

    gemm_bt<1><<<dim3(TSEQ / 128, CDIM / 128), 256, 0, stream>>>(
        Yb, WpT, b_proj, nullptr, nullptr, nullptr, out, TSEQ, CDIM, CDIM);
}

// Round 2
// 328.137 us; speedup vs baseline: 1.4933x; 1.4933x over previous
//
#include <hip/hip_runtime.h>
#include <hip/hip_bf16.h>
#include <cstdint>
#include <cstddef>

#define NHEAD 12
#define TSEQ  4096
#define CDIM  768
#define DHEAD 64

typedef __attribute__((ext_vector_type(8))) short bf16x8;
typedef __attribute__((ext_vector_type(4))) float f32x4;

typedef __attribute__((address_space(1))) void gvoid;
typedef __attribute__((address_space(3))) void lvoid;

static __device__ __forceinline__ unsigned short f2bf(float f) {
    union { float f; uint32_t u; } v; v.f = f;
    uint32_t u = v.u;
    u += 0x7fffu + ((u >> 16) & 1u);   // RNE
    return (unsigned short)(u >> 16);
}

static __device__ __forceinline__ f32x4 mfma16(bf16x8 a, bf16x8 b, f32x4 c) {
    return __builtin_amdgcn_mfma_f32_16x16x32_bf16(a, b, c, 0, 0, 0);
}

// ---------------- conversion kernels ----------------

__global__ void cvt_f32_bf16(const float* __restrict__ in, unsigned short* __restrict__ out, int n4) {
    int i = blockIdx.x * blockDim.x + threadIdx.x;
    int stride = gridDim.x * blockDim.x;
    for (int idx = i; idx < n4; idx += stride) {
        float4 v = reinterpret_cast<const float4*>(in)[idx];
        ushort4 o;
        o.x = f2bf(v.x); o.y = f2bf(v.y); o.z = f2bf(v.z); o.w = f2bf(v.w);
        reinterpret_cast<ushort4*>(out)[idx] = o;
    }
}

// W [K][N] f32  ->  Wt [N][K] bf16
__global__ void transpose_cvt(const float* __restrict__ W, unsigned short* __restrict__ Wt,
                              int K, int N) {
    __shared__ float tile[32][33];
    int n0 = blockIdx.x * 32;
    int k0 = blockIdx.y * 32;
    int tx = threadIdx.x & 31;
    int ty = threadIdx.x >> 5;   // 0..7
    #pragma unroll
    for (int r = ty; r < 32; r += 8)
        tile[r][tx] = W[(size_t)(k0 + r) * N + n0 + tx];
    __syncthreads();
    #pragma unroll
    for (int r = ty; r < 32; r += 8)
        Wt[(size_t)(n0 + r) * K + k0 + tx] = f2bf(tile[tx][r]);
}

// ---------------- GEMM core (A [M][K] bf16, Bt [N][K] bf16) ----------------
// MODE 0: qkv epilogue -> Q[h][t][d], K[h][t][d], Vt[h][d][t] (bf16, +bias)
// MODE 1: proj epilogue -> Out f32 [M][N] (+bias)

template<int MODE>
__global__ __launch_bounds__(256)
void gemm_bt(const unsigned short* __restrict__ A,
             const unsigned short* __restrict__ Bt,
             const float* __restrict__ bias,
             unsigned short* __restrict__ Qb,
             unsigned short* __restrict__ Kb,
             unsigned short* __restrict__ Vt,
             float* __restrict__ Out,
             int M, int N, int K)
{
    __shared__ __align__(16) unsigned short As[128 * 32];
    __shared__ __align__(16) unsigned short Bs[128 * 32];

    const int tid  = threadIdx.x;
    const int lane = tid & 63;
    const int w    = tid >> 6;       // 4 waves
    const int wr   = w >> 1, wc = w & 1;
    const int row0 = blockIdx.x * 128;
    const int col0 = blockIdx.y * 128;
    const int l16  = lane & 15;
    const int lhi  = lane >> 4;

    f32x4 acc[4][4] = {};

    for (int k0 = 0; k0 < K; k0 += 32) {
        __syncthreads();   // previous iteration's LDS reads done
        #pragma unroll
        for (int r = 0; r < 2; ++r) {
            int b    = r * 4096 + w * 1024 + lane * 16;   // byte offset in 8KB tile
            int trow = b >> 6;                            // tile row (64B per row)
            int koff = b & 63;                            // byte offset within row
            const char* gA = (const char*)A  + ((size_t)(row0 + trow) * K + k0) * 2 + koff;
            const char* gB = (const char*)Bt + ((size_t)(col0 + trow) * K + k0) * 2 + koff;
            __builtin_amdgcn_global_load_lds((gvoid*)gA,
                (lvoid*)((char*)As + r * 4096 + w * 1024), 16, 0, 0);
            __builtin_amdgcn_global_load_lds((gvoid*)gB,
                (lvoid*)((char*)Bs + r * 4096 + w * 1024), 16, 0, 0);
        }
        __syncthreads();   // drains vmcnt(0): staged data visible

        bf16x8 a[4], bfr[4];
        #pragma unroll
        for (int m = 0; m < 4; ++m) {
            int row = wr * 64 + m * 16 + l16;
            a[m] = *reinterpret_cast<const bf16x8*>(&As[row * 32 + lhi * 8]);
        }
        #pragma unroll
        for (int n = 0; n < 4; ++n) {
            int col = wc * 64 + n * 16 + l16;
            bfr[n] = *reinterpret_cast<const bf16x8*>(&Bs[col * 32 + lhi * 8]);
        }
        #pragma unroll
        for (int m = 0; m < 4; ++m)
            #pragma unroll
            for (int n = 0; n < 4; ++n)
                acc[m][n] = mfma16(a[m], bfr[n], acc[m][n]);
    }

    // epilogue: C[row][col], row = trow_base + (lhi*4 + j), col = ncol
    #pragma unroll
    for (int m = 0; m < 4; ++m) {
        int trow = row0 + wr * 64 + m * 16 + lhi * 4;
        #pragma unroll
        for (int n = 0; n < 4; ++n) {
            int ncol = col0 + wc * 64 + n * 16 + l16;
            float bv = bias[ncol];
            #pragma unroll
            for (int j = 0; j < 4; ++j) {
                float v = acc[m][n][j] + bv;
                int t = trow + j;
                if (MODE == 0) {
                    unsigned short hv = f2bf(v);
                    if (ncol < 768) {
                        int hh = ncol >> 6, d = ncol & 63;
                        Qb[((size_t)hh * TSEQ + t) * 64 + d] = hv;
                    } else if (ncol < 1536) {
                        int c = ncol - 768; int hh = c >> 6, d = c & 63;
                        Kb[((size_t)hh * TSEQ + t) * 64 + d] = hv;
                    } else {
                        int c = ncol - 1536; int hh = c >> 6, d = c & 63;
                        Vt[((size_t)hh * 64 + d) * TSEQ + t] = hv;
                    }
                } else {
                    Out[(size_t)t * N + ncol] = v;
                }
            }
        }
    }
}

// ---------------- flash attention (causal) ----------------
// grid: 768 blocks = 64 q-tiles (desc order, biggest first) x 12 heads.
// block = 256 threads = 4 waves; wave w owns 16 q rows: q0 = qb*64 + w*16.
// KV tiles of 64. All 4 waves in a block have IDENTICAL trip count (qb+1).
// No __syncthreads (Plds regions disjoint per wave).

__global__ __launch_bounds__(256)
void attn_fwd(const unsigned short* __restrict__ Qb,
              const unsigned short* __restrict__ Kb,
              const unsigned short* __restrict__ Vt,
              unsigned short* __restrict__ Y)
{
    __shared__ __align__(16) unsigned short Plds[4][16 * 72];  // padded: 144B rows

    const int tid  = threadIdx.x;
    const int lane = tid & 63;
    const int w    = tid >> 6;
    const int h    = blockIdx.x % NHEAD;          // head inner
    const int qb   = 63 - (blockIdx.x / NHEAD);   // biggest q-tile first
    const int q0   = qb * 64 + w * 16;
    const int l16  = lane & 15, lhi = lane >> 4;

    const unsigned short* Qh = Qb + (size_t)h * TSEQ * 64;
    const unsigned short* Kh = Kb + (size_t)h * TSEQ * 64;
    const unsigned short* Vh = Vt + (size_t)h * 64 * TSEQ;

    // Q fragments (A operand), 16 q-rows: [k-step]
    bf16x8 qf[2];
    #pragma unroll
    for (int ss = 0; ss < 2; ++ss)
        qf[ss] = *reinterpret_cast<const bf16x8*>(
            &Qh[(size_t)(q0 + l16) * 64 + ss * 32 + lhi * 8]);

    f32x4 o[4] = {};
    float mrun[4], lrun[4];
    #pragma unroll
    for (int j = 0; j < 4; ++j) { mrun[j] = -1e30f; lrun[j] = 0.f; }

    const int ntiles = qb + 1;

    // preload K tile 0 fragments (B operand): [k-step][n-frag]
    bf16x8 kf[2][4];
    #pragma unroll
    for (int ss = 0; ss < 2; ++ss)
        #pragma unroll
        for (int n = 0; n < 4; ++n)
            kf[ss][n] = *reinterpret_cast<const bf16x8*>(
                &Kh[(size_t)(n * 16 + l16) * 64 + ss * 32 + lhi * 8]);

    for (int kt = 0; kt < ntiles; ++kt) {
        const int kv0 = kt * 64;

        // ---- S = Q K^T over d=64 (16 q x 64 kv) ----
        f32x4 s[4] = {};
        #pragma unroll
        for (int ss = 0; ss < 2; ++ss)
            #pragma unroll
            for (int n = 0; n < 4; ++n)
                s[n] = mfma16(qf[ss], kf[ss][n], s[n]);

        // ---- prefetch next K tile (latency hides under softmax) ----
        if (kt + 1 < ntiles) {
            const int nv0 = kv0 + 64;
            #pragma unroll
            for (int ss = 0; ss < 2; ++ss)
                #pragma unroll
                for (int n = 0; n < 4; ++n)
                    kf[ss][n] = *reinterpret_cast<const bf16x8*>(
                        &Kh[(size_t)(nv0 + n * 16 + l16) * 64 + ss * 32 + lhi * 8]);
        }

        // ---- V fragments for current tile (issue early) ----
        bf16x8 vf[2][4];
        #pragma unroll
        for (int ks = 0; ks < 2; ++ks)
            #pragma unroll
            for (int df = 0; df < 4; ++df)
                vf[ks][df] = *reinterpret_cast<const bf16x8*>(
                    &Vh[(size_t)(df * 16 + l16) * TSEQ + kv0 + ks * 32 + lhi * 8]);

        // ---- online softmax; lane owns 4 q-rows (j), 4 kv cols per row (n) ----
        const bool diag = (kt == ntiles - 1);
        #pragma unroll
        for (int j = 0; j < 4; ++j) {
            float sv[4];
            #pragma unroll
            for (int n = 0; n < 4; ++n) sv[n] = s[n][j] * 0.125f;
            if (diag) {
                int qrel = w * 16 + lhi * 4 + j;   // q - kv0
                #pragma unroll
                for (int n = 0; n < 4; ++n)
                    if (n * 16 + l16 > qrel) sv[n] = -1e30f;
            }
            float mx = fmaxf(fmaxf(sv[0], sv[1]), fmaxf(sv[2], sv[3]));
            #pragma unroll
            for (int off = 8; off >= 1; off >>= 1)
                mx = fmaxf(mx, __shfl_xor(mx, off));
            float mnew = fmaxf(mrun[j], mx);
            float corr = __expf(mrun[j] - mnew);
            float p[4], ps = 0.f;
            #pragma unroll
            for (int n = 0; n < 4; ++n) { p[n] = __expf(sv[n] - mnew); ps += p[n]; }
            #pragma unroll
            for (int off = 8; off >= 1; off >>= 1)
                ps += __shfl_xor(ps, off);
            lrun[j] = lrun[j] * corr + ps;
            mrun[j] = mnew;
            #pragma unroll
            for (int df = 0; df < 4; ++df)
                o[df][j] *= corr;
            int row = lhi * 4 + j;
            #pragma unroll
            for (int n = 0; n < 4; ++n)
                Plds[w][row * 72 + n * 16 + l16] = f2bf(p[n]);
        }
        asm volatile("s_waitcnt lgkmcnt(0)" ::: "memory");

        // ---- O += P V ----
        bf16x8 pa[2];
        #pragma unroll
        for (int ks = 0; ks < 2; ++ks)
            pa[ks] = *reinterpret_cast<const bf16x8*>(
                &Plds[w][l16 * 72 + ks * 32 + lhi * 8]);
        #pragma unroll
        for (int ks = 0; ks < 2; ++ks)
            #pragma unroll
            for (int df = 0; df < 4; ++df)
                o[df] = mfma16(pa[ks], vf[ks][df], o[df]);
    }

    // ---- epilogue: y[t][h*64+d] bf16 ----
    #pragma unroll
    for (int df = 0; df < 4; ++df) {
        #pragma unroll
        for (int j = 0; j < 4; ++j) {
            float v = o[df][j] / lrun[j];
            int t = q0 + lhi * 4 + j;
            int c = h * 64 + df * 16 + l16;
            Y[(size_t)t * CDIM + c] = f2bf(v);
        }
    }
}

// ---------------- launch ----------------

extern "C" void kernel_launch(void* const* d_in, const int* in_sizes, int n_in,
                              void* d_out, int out_size, void* d_ws, size_t ws_size,
                              hipStream_t stream) {
    const float* x      = (const float*)d_in[0];
    const float* w_attn = (const float*)d_in[1];
    const float* b_attn = (const float*)d_in[2];
    const float* w_proj = (const float*)d_in[3];
    const float* b_proj = (const float*)d_in[4];
    float* out = (float*)d_out;

    char* ws = (char*)d_ws;
    unsigned short* xb  = (unsigned short*)(ws + 0);         // 4096*768
    unsigned short* WaT = (unsigned short*)(ws + 6291456);   // 2304*768
    unsigned short* WpT = (unsigned short*)(ws + 9830400);   // 768*768
    unsigned short* Qb  = (unsigned short*)(ws + 11010048);  // 12*4096*64
    unsigned short* Kb  = (unsigned short*)(ws + 17301504);  // 12*4096*64
    unsigned short* Vt  = (unsigned short*)(ws + 23592960);  // 12*64*4096
    unsigned short* Yb  = (unsigned short*)(ws + 29884416);  // 4096*768

    cvt_f32_bf16<<<2048, 256, 0, stream>>>(x, xb, TSEQ * CDIM / 4);
    transpose_cvt<<<dim3(2304 / 32, 768 / 32), 256, 0, stream>>>(w_attn, WaT, 768, 2304);
    transpose_cvt<<<dim3(768 / 32, 768 / 32), 256, 0, stream>>>(w_proj, WpT, 768, 768);

    gemm_bt<0><<<dim3(TSEQ / 128, 2304 / 128), 256, 0, stream>>>(
        xb, WaT, b_attn, Qb, Kb, Vt, nullptr, TSEQ, 2304, CDIM);

    attn_fwd<<<NHEAD * (TSEQ / 64), 256, 0, stream>>>(Qb, Kb, Vt, Yb);

    gemm_bt<1><<<dim3(TSEQ / 128, CDIM / 128), 256, 0, stream>>>(
        Yb, WpT, b_proj, nullptr, nullptr, nullptr, out, TSEQ, CDIM, CDIM);
}

// Round 3
// 250.781 us; speedup vs baseline: 1.9539x; 1.3085x over previous
//
#include <hip/hip_runtime.h>
#include <hip/hip_bf16.h>
#include <cstdint>
#include <cstddef>

#define NHEAD 12
#define TSEQ  4096
#define CDIM  768

typedef __attribute__((ext_vector_type(8))) short bf16x8;
typedef __attribute__((ext_vector_type(4))) float f32x4;
typedef __attribute__((ext_vector_type(16))) float f32x16;
typedef __attribute__((ext_vector_type(2))) unsigned int u32x2;

typedef __attribute__((address_space(1))) void gvoid;
typedef __attribute__((address_space(3))) void lvoid;

#define QSCALE 0.1803368801111204f   /* 0.125 * log2(e) */

static __device__ __forceinline__ unsigned short f2bf(float f) {
    union { float f; uint32_t u; } v; v.f = f;
    uint32_t u = v.u;
    u += 0x7fffu + ((u >> 16) & 1u);   // RNE
    return (unsigned short)(u >> 16);
}

static __device__ __forceinline__ f32x4 mfma16(bf16x8 a, bf16x8 b, f32x4 c) {
    return __builtin_amdgcn_mfma_f32_16x16x32_bf16(a, b, c, 0, 0, 0);
}
static __device__ __forceinline__ f32x16 mfma32(bf16x8 a, bf16x8 b, f32x16 c) {
    return __builtin_amdgcn_mfma_f32_32x32x16_bf16(a, b, c, 0, 0, 0);
}
static __device__ __forceinline__ unsigned cvt_pk_bf16(float lo, float hi) {
    unsigned r;
    asm("v_cvt_pk_bf16_f32 %0, %1, %2" : "=v"(r) : "v"(lo), "v"(hi));
    return r;
}

// ---------------- conversion kernels ----------------

__global__ void cvt_f32_bf16(const float* __restrict__ in, unsigned short* __restrict__ out, int n4) {
    int i = blockIdx.x * blockDim.x + threadIdx.x;
    int stride = gridDim.x * blockDim.x;
    for (int idx = i; idx < n4; idx += stride) {
        float4 v = reinterpret_cast<const float4*>(in)[idx];
        ushort4 o;
        o.x = f2bf(v.x); o.y = f2bf(v.y); o.z = f2bf(v.z); o.w = f2bf(v.w);
        reinterpret_cast<ushort4*>(out)[idx] = o;
    }
}

// W [K][N] f32  ->  Wt [N][K] bf16
__global__ void transpose_cvt(const float* __restrict__ W, unsigned short* __restrict__ Wt,
                              int K, int N) {
    __shared__ float tile[32][33];
    int n0 = blockIdx.x * 32;
    int k0 = blockIdx.y * 32;
    int tx = threadIdx.x & 31;
    int ty = threadIdx.x >> 5;   // 0..7
    #pragma unroll
    for (int r = ty; r < 32; r += 8)
        tile[r][tx] = W[(size_t)(k0 + r) * N + n0 + tx];
    __syncthreads();
    #pragma unroll
    for (int r = ty; r < 32; r += 8)
        Wt[(size_t)(n0 + r) * K + k0 + tx] = f2bf(tile[tx][r]);
}

// ---------------- GEMM core (A [M][K] bf16, Bt [N][K] bf16) ----------------
// MODE 0: qkv epilogue -> Q[h][t][d] (pre-scaled), K[h][t][d], Vt[h][d][t]
// MODE 1: proj epilogue -> Out f32 [M][N] (+bias)

template<int MODE>
__global__ __launch_bounds__(256)
void gemm_bt(const unsigned short* __restrict__ A,
             const unsigned short* __restrict__ Bt,
             const float* __restrict__ bias,
             unsigned short* __restrict__ Qb,
             unsigned short* __restrict__ Kb,
             unsigned short* __restrict__ Vt,
             float* __restrict__ Out,
             int M, int N, int K)
{
    __shared__ __align__(16) unsigned short As[128 * 32];
    __shared__ __align__(16) unsigned short Bs[128 * 32];

    const int tid  = threadIdx.x;
    const int lane = tid & 63;
    const int w    = tid >> 6;       // 4 waves
    const int wr   = w >> 1, wc = w & 1;
    const int row0 = blockIdx.x * 128;
    const int col0 = blockIdx.y * 128;
    const int l16  = lane & 15;
    const int lhi  = lane >> 4;

    f32x4 acc[4][4] = {};

    for (int k0 = 0; k0 < K; k0 += 32) {
        __syncthreads();
        #pragma unroll
        for (int r = 0; r < 2; ++r) {
            int b    = r * 4096 + w * 1024 + lane * 16;
            int trow = b >> 6;
            int koff = b & 63;
            const char* gA = (const char*)A  + ((size_t)(row0 + trow) * K + k0) * 2 + koff;
            const char* gB = (const char*)Bt + ((size_t)(col0 + trow) * K + k0) * 2 + koff;
            __builtin_amdgcn_global_load_lds((gvoid*)gA,
                (lvoid*)((char*)As + r * 4096 + w * 1024), 16, 0, 0);
            __builtin_amdgcn_global_load_lds((gvoid*)gB,
                (lvoid*)((char*)Bs + r * 4096 + w * 1024), 16, 0, 0);
        }
        __syncthreads();

        bf16x8 a[4], bfr[4];
        #pragma unroll
        for (int m = 0; m < 4; ++m) {
            int row = wr * 64 + m * 16 + l16;
            a[m] = *reinterpret_cast<const bf16x8*>(&As[row * 32 + lhi * 8]);
        }
        #pragma unroll
        for (int n = 0; n < 4; ++n) {
            int col = wc * 64 + n * 16 + l16;
            bfr[n] = *reinterpret_cast<const bf16x8*>(&Bs[col * 32 + lhi * 8]);
        }
        #pragma unroll
        for (int m = 0; m < 4; ++m)
            #pragma unroll
            for (int n = 0; n < 4; ++n)
                acc[m][n] = mfma16(a[m], bfr[n], acc[m][n]);
    }

    #pragma unroll
    for (int m = 0; m < 4; ++m) {
        int trow = row0 + wr * 64 + m * 16 + lhi * 4;
        #pragma unroll
        for (int n = 0; n < 4; ++n) {
            int ncol = col0 + wc * 64 + n * 16 + l16;
            float bv = bias[ncol];
            #pragma unroll
            for (int j = 0; j < 4; ++j) {
                float v = acc[m][n][j] + bv;
                int t = trow + j;
                if (MODE == 0) {
                    if (ncol < 768) {
                        int hh = ncol >> 6, d = ncol & 63;
                        Qb[((size_t)hh * TSEQ + t) * 64 + d] = f2bf(v * QSCALE);
                    } else if (ncol < 1536) {
                        int c = ncol - 768; int hh = c >> 6, d = c & 63;
                        Kb[((size_t)hh * TSEQ + t) * 64 + d] = f2bf(v);
                    } else {
                        int c = ncol - 1536; int hh = c >> 6, d = c & 63;
                        Vt[((size_t)hh * 64 + d) * TSEQ + t] = f2bf(v);
                    }
                } else {
                    Out[(size_t)t * N + ncol] = v;
                }
            }
        }
    }
}

// ---------------- flash attention (causal, swapped-operand, zero-LDS) -------
// grid: 1536 blocks = 128 q-blocks of 32 (desc order) x 12 heads; 1 wave each.
// Lane layout (32x32x16 mfma): col = lane&31 = q-index; lane and lane+32 hold
// disjoint halves of each kv/d row dimension. Softmax is lane-local + one
// permlane32_swap. P->bf16 B-fragments via cvt_pk + permlane32_swap (T12).

__global__ __launch_bounds__(64)
void attn_fwd(const unsigned short* __restrict__ Qb,
              const unsigned short* __restrict__ Kb,
              const unsigned short* __restrict__ Vt,
              unsigned short* __restrict__ Y)
{
    const int lane = threadIdx.x & 63;
    const int l31  = lane & 31;
    const int hi   = lane >> 5;
    const int bid  = blockIdx.x;
    const int h    = bid % NHEAD;
    const int qb   = 127 - bid / NHEAD;     // biggest q-block first
    const int q0   = qb * 32;
    const int ntiles = q0 / 64 + 1;

    const unsigned short* Qh = Qb + (size_t)h * TSEQ * 64;
    const unsigned short* Kh = Kb + (size_t)h * TSEQ * 64;
    const unsigned short* Vh = Vt + (size_t)h * 64 * TSEQ;

    // Q^T B-fragments: Q[q0+l31][ks*16 + hi*8 + j]   (Q pre-scaled by QSCALE)
    bf16x8 qf[4];
    #pragma unroll
    for (int ks = 0; ks < 4; ++ks)
        qf[ks] = *reinterpret_cast<const bf16x8*>(
            &Qh[(size_t)(q0 + l31) * 64 + ks * 16 + hi * 8]);

    f32x16 o0 = {}, o1 = {};
    float mrun = -1e30f, lrun = 0.f;

    bf16x8 kfA[2][4], kfB[2][4];
    #pragma unroll
    for (int sub = 0; sub < 2; ++sub)
        #pragma unroll
        for (int ks = 0; ks < 4; ++ks)
            kfA[sub][ks] = *reinterpret_cast<const bf16x8*>(
                &Kh[(size_t)(sub * 32 + l31) * 64 + ks * 16 + hi * 8]);

    auto body = [&](int kt, bf16x8 (&kc)[2][4], bf16x8 (&kn)[2][4]) {
        const int kv0 = kt * 64;

        // V fragments (A-operand of O^T): V^T[d][kv], contiguous in Vt[d][t]
        bf16x8 vf[2][4];
        #pragma unroll
        for (int d = 0; d < 2; ++d)
            #pragma unroll
            for (int ks = 0; ks < 4; ++ks)
                vf[d][ks] = *reinterpret_cast<const bf16x8*>(
                    &Vh[(size_t)(d * 32 + l31) * TSEQ + kv0 + ks * 16 + hi * 8]);

        // S^T = K · Q^T  (rows = kv, cols = q)
        f32x16 s0 = {}, s1 = {};
        #pragma unroll
        for (int ks = 0; ks < 4; ++ks) {
            s0 = mfma32(kc[0][ks], qf[ks], s0);
            s1 = mfma32(kc[1][ks], qf[ks], s1);
        }

        // prefetch next K tile into the other buffer
        if (kt + 1 < ntiles) {
            const int nv0 = kv0 + 64;
            #pragma unroll
            for (int sub = 0; sub < 2; ++sub)
                #pragma unroll
                for (int ks = 0; ks < 4; ++ks)
                    kn[sub][ks] = *reinterpret_cast<const bf16x8*>(
                        &Kh[(size_t)(nv0 + sub * 32 + l31) * 64 + ks * 16 + hi * 8]);
        }

        float sv[32];
        #pragma unroll
        for (int i = 0; i < 16; ++i) { sv[i] = s0[i]; sv[16 + i] = s1[i]; }

        if (kt == ntiles - 1) {           // diagonal tile: causal mask
            const int qrel = q0 + l31 - kv0;
            const int h4 = hi * 4;
            #pragma unroll
            for (int i = 0; i < 32; ++i) {
                int kvbase = (i >> 4) * 32 + (i & 3) + 8 * ((i >> 2) & 3);
                if (kvbase + h4 > qrel) sv[i] = -1e30f;
            }
        }

        // row max: in-lane tree + cross-half swap
        float t[16];
        #pragma unroll
        for (int i = 0; i < 16; ++i) t[i] = fmaxf(sv[i], sv[i + 16]);
        #pragma unroll
        for (int s = 8; s >= 1; s >>= 1)
            #pragma unroll
            for (int i = 0; i < s; ++i) t[i] = fmaxf(t[i], t[i + s]);
        float mx;
        {
            union { float f; unsigned u; } c; c.f = t[0];
            u32x2 r = __builtin_amdgcn_permlane32_swap(c.u, c.u, false, false);
            union { unsigned u; float f; } ra, rb; ra.u = r.x; rb.u = r.y;
            mx = fmaxf(ra.f, rb.f);
        }
        float mnew = fmaxf(mrun, mx);
        float corr = exp2f(mrun - mnew);
        mrun = mnew;

        float e[32];
        #pragma unroll
        for (int i = 0; i < 32; ++i) e[i] = exp2f(sv[i] - mnew);

        // row sum: in-lane tree + cross-half swap
        float u[16];
        #pragma unroll
        for (int i = 0; i < 16; ++i) u[i] = e[i] + e[i + 16];
        #pragma unroll
        for (int s = 8; s >= 1; s >>= 1)
            #pragma unroll
            for (int i = 0; i < s; ++i) u[i] += u[i + s];
        float ps;
        {
            union { float f; unsigned u; } c; c.f = u[0];
            u32x2 r = __builtin_amdgcn_permlane32_swap(c.u, c.u, false, false);
            union { unsigned u; float f; } ra, rb; ra.u = r.x; rb.u = r.y;
            ps = ra.f + rb.f;
        }
        lrun = lrun * corr + ps;

        // rescale O
        #pragma unroll
        for (int i = 0; i < 16; ++i) { o0[i] *= corr; o1[i] *= corr; }

        // pack P^T B-fragments: per 16-kv step, 4 cvt_pk + 2 permlane32_swap
        bf16x8 pw[4];
        #pragma unroll
        for (int ks = 0; ks < 4; ++ks) {
            const int eb = (ks >> 1) * 16 + (ks & 1) * 8;
            u32x2 r02 = __builtin_amdgcn_permlane32_swap(
                cvt_pk_bf16(e[eb + 0], e[eb + 1]), cvt_pk_bf16(e[eb + 4], e[eb + 5]),
                false, false);
            u32x2 r13 = __builtin_amdgcn_permlane32_swap(
                cvt_pk_bf16(e[eb + 2], e[eb + 3]), cvt_pk_bf16(e[eb + 6], e[eb + 7]),
                false, false);
            union { unsigned w[4]; bf16x8 v; } pk;
            pk.w[0] = r02.x; pk.w[1] = r13.x; pk.w[2] = r02.y; pk.w[3] = r13.y;
            pw[ks] = pk.v;
        }

        // O^T += V^T · P^T
        #pragma unroll
        for (int ks = 0; ks < 4; ++ks) {
            o0 = mfma32(vf[0][ks], pw[ks], o0);
            o1 = mfma32(vf[1][ks], pw[ks], o1);
        }
    };

    int kt = 0;
    for (; kt + 2 <= ntiles; kt += 2) {
        body(kt, kfA, kfB);
        body(kt + 1, kfB, kfA);
    }
    if (kt < ntiles) body(kt, kfA, kfB);

    // epilogue: y[t][h*64 + d], d = dsub*32 + (rr&3) + 8*(rr>>2) + 4*hi
    float inv = 1.0f / lrun;
    const int trow = q0 + l31;
    #pragma unroll
    for (int d = 0; d < 2; ++d) {
        #pragma unroll
        for (int p = 0; p < 8; ++p) {
            const int rr = p * 2;
            float v0 = (d ? o1 : o0)[rr] * inv;
            float v1 = (d ? o1 : o0)[rr + 1] * inv;
            int c = h * 64 + d * 32 + (rr & 3) + 8 * (rr >> 2) + hi * 4;
            unsigned wd = cvt_pk_bf16(v0, v1);
            *reinterpret_cast<unsigned*>(
                const_cast<unsigned short*>(&Y[(size_t)trow * CDIM + c])) = wd;
        }
    }
}

// ---------------- launch ----------------

extern "C" void kernel_launch(void* const* d_in, const int* in_sizes, int n_in,
                              void* d_out, int out_size, void* d_ws, size_t ws_size,
                              hipStream_t stream) {
    const float* x      = (const float*)d_in[0];
    const float* w_attn = (const float*)d_in[1];
    const float* b_attn = (const float*)d_in[2];
    const float* w_proj = (const float*)d_in[3];
    const float* b_proj = (const float*)d_in[4];
    float* out = (float*)d_out;

    char* ws = (char*)d_ws;
    unsigned short* xb  = (unsigned short*)(ws + 0);         // 4096*768
    unsigned short* WaT = (unsigned short*)(ws + 6291456);   // 2304*768
    unsigned short* WpT = (unsigned short*)(ws + 9830400);   // 768*768
    unsigned short* Qb  = (unsigned short*)(ws + 11010048);  // 12*4096*64
    unsigned short* Kb  = (unsigned short*)(ws + 17301504);  // 12*4096*64
    unsigned short* Vt  = (unsigned short*)(ws + 23592960);  // 12*64*4096
    unsigned short* Yb  = (unsigned short*)(ws + 29884416);  // 4096*768

    cvt_f32_bf16<<<2048, 256, 0, stream>>>(x, xb, TSEQ * CDIM / 4);
    transpose_cvt<<<dim3(2304 / 32, 768 / 32), 256, 0, stream>>>(w_attn, WaT, 768, 2304);
    transpose_cvt<<<dim3(768 / 32, 768 / 32), 256, 0, stream>>>(w_proj, WpT, 768, 768);

    gemm_bt<0><<<dim3(TSEQ / 128, 2304 / 128), 256, 0, stream>>>(
        xb, WaT, b_attn, Qb, Kb, Vt, nullptr, TSEQ, 2304, CDIM);

    attn_fwd<<<NHEAD * (TSEQ / 32), 64, 0, stream>>>(Qb, Kb, Vt, Yb);

    gemm_bt<1><<<dim3(TSEQ / 128, CDIM / 128), 256, 0, stream>>>(
        Yb, WpT, b_proj, nullptr, nullptr, nullptr, out, TSEQ, CDIM, CDIM);
}